// Round 11
// baseline (5762.920 us; speedup 1.0000x reference)
//
#include <hip/hip_runtime.h>
#include <math.h>

#define BB 256
#define KK 256
#define VV 256
#define MM 4000
#define TOPK 8

// ---- DIAGNOSTIC ROUND: rep-loops inflate k_sims/k_topk/k_retr dispatches
// past the harness's ~650us poison fills so they surface in the rocprof top-5
// with per-dispatch counters. Each rep is bit-identical and idempotent.
#define REP_SIMS 90
#define REP_TOPK 100
#define REP_RETR 16

// K1: e64 = tanh(qk @ Wk^T + bk); qn64 = e64 / max(||e64||, 1e-8)
// (verbatim from round-2/4 PASSED kernel)
__global__ void k_proj(const float* __restrict__ qk, const float* __restrict__ Wk,
                       const float* __restrict__ bk, double* __restrict__ e64,
                       double* __restrict__ qn64) {
    int b = blockIdx.x, j = threadIdx.x;
    __shared__ float q[KK];
    __shared__ double red[256];
    q[j] = qk[b * KK + j];
    __syncthreads();
    const float* w = Wk + (size_t)j * KK;
    double acc = 0.0;
#pragma unroll 4
    for (int d = 0; d < KK; ++d) acc += (double)q[d] * (double)w[d];
    double val = tanh(acc + (double)bk[j]);
    e64[b * KK + j] = val;
    red[j] = val * val;
    __syncthreads();
    for (int s = 128; s > 0; s >>= 1) {
        if (j < s) red[j] += red[j + s];
        __syncthreads();
    }
    double nrm = fmax(sqrt(red[0]), 1e-8);
    qn64[b * KK + j] = val / nrm;
}

// K2: gather stored_keys = A[midx[m], k, 0]; kn64 = row / max(||row||, 1e-8)
// (verbatim from round-2/4 PASSED kernel; NOT looped — a rep-loop would turn
// its cold gather L3-warm and under-measure; inferred as remainder instead)
__global__ void k_kn(const float* __restrict__ A, const int* __restrict__ midx,
                     double* __restrict__ kn64) {
    int m = blockIdx.x, t = threadIdx.x;
    size_t n = (size_t)midx[m];
    double val = (double)A[n * (size_t)(KK * VV) + (size_t)t * VV];
    __shared__ double red[256];
    red[t] = val * val;
    __syncthreads();
    for (int s = 128; s > 0; s >>= 1) {
        if (t < s) red[t] += red[t + s];
        __syncthreads();
    }
    double nrm = fmax(sqrt(red[0]), 1e-8);
    kn64[(size_t)m * KK + t] = val / nrm;
}

// K3 v3b: sims64 = qn64 @ kn64^T, f64. (round-9 PASSED kernel + rep loop)
#define BMS 16
#define BNS 64
#define KS  16
__global__ void __launch_bounds__(64) k_sims(
        const double* __restrict__ qn, const double* __restrict__ kn,
        double* __restrict__ sims) {
    __shared__ double qsT[2][KS][BMS + 2];
    __shared__ double ksT[2][KS][BNS + 8];
    int tid = threadIdx.x;
    int tx = tid & 15, ty = tid >> 4;
    int m0 = blockIdx.x * BNS, b0 = blockIdx.y * BMS;
    int qr = tid & 15;
    int qc = (tid >> 4) * 4;
    int krr = tid >> 3;
    int kc = (tid & 7) * 2;
    const double* qrow = qn + (size_t)(b0 + qr) * KK;
    int pb = tx * 4 + (tx >> 2) * 2;

    for (int rep = 0; rep < REP_SIMS; ++rep) {
        double acc[4][4] = {};
        {
            double qreg[4]; double2 kreg[8]; int rr[8];
#pragma unroll
            for (int j = 0; j < 4; ++j) qreg[j] = qrow[qc + j];
#pragma unroll
            for (int s = 0; s < 8; ++s) {
                int r = krr + s * 8; rr[s] = r;
                int mrow = m0 + r;
                const double* kp = kn + (size_t)(mrow < MM ? mrow : 0) * KK + kc;
                kreg[s] = (mrow < MM) ? *(const double2*)kp : make_double2(0.0, 0.0);
            }
#pragma unroll
            for (int j = 0; j < 4; ++j) qsT[0][qc + j][qr] = qreg[j];
#pragma unroll
            for (int s = 0; s < 8; ++s) {
                int p = rr[s] + (rr[s] >> 4) * 2;
                ksT[0][kc][p]     = kreg[s].x;
                ksT[0][kc + 1][p] = kreg[s].y;
            }
        }
        __syncthreads();

        for (int t = 0; t < KK / KS; ++t) {
            int cur = t & 1;
            double qreg[4]; double2 kreg[8]; int rr[8];
            bool have = (t < KK / KS - 1);
            if (have) {
                int kk2 = (t + 1) * KS;
#pragma unroll
                for (int j = 0; j < 4; ++j) qreg[j] = qrow[kk2 + qc + j];
#pragma unroll
                for (int s = 0; s < 8; ++s) {
                    int r = krr + s * 8; rr[s] = r;
                    int mrow = m0 + r;
                    const double* kp = kn + (size_t)(mrow < MM ? mrow : 0) * KK + kk2 + kc;
                    kreg[s] = (mrow < MM) ? *(const double2*)kp : make_double2(0.0, 0.0);
                }
            }
#pragma unroll
            for (int i = 0; i < KS; ++i) {
                double qv[4], kv[4];
                *(double2*)&qv[0] = *(const double2*)&qsT[cur][i][ty * 4];
                *(double2*)&qv[2] = *(const double2*)&qsT[cur][i][ty * 4 + 2];
                *(double2*)&kv[0] = *(const double2*)&ksT[cur][i][pb];
                *(double2*)&kv[2] = *(const double2*)&ksT[cur][i][pb + 2];
#pragma unroll
                for (int a = 0; a < 4; ++a)
#pragma unroll
                    for (int c = 0; c < 4; ++c)
                        acc[a][c] += qv[a] * kv[c];
            }
            if (have) {
                int nxt = cur ^ 1;
#pragma unroll
                for (int j = 0; j < 4; ++j) qsT[nxt][qc + j][qr] = qreg[j];
#pragma unroll
                for (int s = 0; s < 8; ++s) {
                    int p = rr[s] + (rr[s] >> 4) * 2;
                    ksT[nxt][kc][p]     = kreg[s].x;
                    ksT[nxt][kc + 1][p] = kreg[s].y;
                }
            }
            __syncthreads();
        }
#pragma unroll
        for (int a = 0; a < 4; ++a) {
            int bb = b0 + ty * 4 + a;
#pragma unroll
            for (int c = 0; c < 4; ++c) {
                int mm2 = m0 + tx * 4 + c;
                if (mm2 < MM) sims[(size_t)bb * MM + mm2] = acc[a][c];
            }
        }
        __syncthreads();
    }
}

// K4: per-row top-8 in f64 + confidences (round-2 PASSED kernel + rep loop)
__global__ void k_topk(const double* __restrict__ sims, const int* __restrict__ midx,
                       const float* __restrict__ usage, float* __restrict__ out_conf,
                       float* __restrict__ out_sims, int* __restrict__ acts) {
    int b = blockIdx.x, t = threadIdx.x;
    __shared__ double sv[256 * TOPK];
    __shared__ int si[256 * TOPK];
    for (int rep = 0; rep < REP_TOPK; ++rep) {
        double v[TOPK];
        int id[TOPK];
#pragma unroll
        for (int i = 0; i < TOPK; ++i) { v[i] = -INFINITY; id[i] = 0x7fffffff; }
        const double* row = sims + (size_t)b * MM;
        for (int m = t; m < MM; m += 256) {
            double x = row[m];
            if (x > v[TOPK - 1]) {
                v[TOPK - 1] = x; id[TOPK - 1] = m;
#pragma unroll
                for (int i = TOPK - 1; i > 0; --i) {
                    if (v[i] > v[i - 1]) {
                        double tv = v[i]; v[i] = v[i - 1]; v[i - 1] = tv;
                        int ti = id[i]; id[i] = id[i - 1]; id[i - 1] = ti;
                    }
                }
            }
        }
#pragma unroll
        for (int i = 0; i < TOPK; ++i) { sv[t * TOPK + i] = v[i]; si[t * TOPK + i] = id[i]; }
        __syncthreads();
        for (int stride = 128; stride > 0; stride >>= 1) {
            if (t < stride) {
                double* av = &sv[t * TOPK];
                int*    ai = &si[t * TOPK];
                double* bv = &sv[(t + stride) * TOPK];
                int*    bi = &si[(t + stride) * TOPK];
                double mv[TOPK]; int mi[TOPK];
                int pa = 0, pb = 0;
#pragma unroll
                for (int i = 0; i < TOPK; ++i) {
                    double va = av[pa], vb = bv[pb];
                    bool takeA = (va > vb) || (va == vb && ai[pa] < bi[pb]);
                    if (takeA) { mv[i] = va; mi[i] = ai[pa]; ++pa; }
                    else       { mv[i] = vb; mi[i] = bi[pb]; ++pb; }
                }
#pragma unroll
                for (int i = 0; i < TOPK; ++i) { av[i] = mv[i]; ai[i] = mi[i]; }
            }
            __syncthreads();
        }
        if (t < TOPK) {
            double val = sv[t];
            int idx = si[t];
            int actual = midx[idx];
            out_sims[b * TOPK + t] = (float)val;
            out_conf[b * TOPK + t] = (float)(val * (1.0 + log1p((double)usage[actual])));
            acts[b * TOPK + t] = actual;
        }
        __syncthreads();
    }
}

// K5: retrieved[b,k,v] = sum_d e[b,d] * A[acts[b,k], d, v]
// (round-4/9 PASSED kernel — dedup reverted — + rep loop)
__global__ void __launch_bounds__(256) k_retr(
        const float* __restrict__ A, const double* __restrict__ e64,
        const int* __restrict__ acts, float* __restrict__ out) {
    int bk_ = blockIdx.x;        // b*TOPK + k
    int b = bk_ >> 3;
    int tid = threadIdx.x;
    int w = tid >> 6, l = tid & 63;
    size_t n = (size_t)acts[bk_];
    const float* Ap = A + n * (size_t)(KK * VV);
    __shared__ float es[KK];
    __shared__ float part[4][64][4];
    for (int rep = 0; rep < REP_RETR; ++rep) {
        es[tid] = (float)e64[b * KK + tid];
        __syncthreads();
        float ax = 0.f, ay = 0.f, az = 0.f, aw = 0.f;
        const float* base = Ap + (size_t)(w * 64) * VV + 4 * l;
#pragma unroll 8
        for (int dd = 0; dd < 64; ++dd) {
            float ev = es[w * 64 + dd];
            const float4 a = *reinterpret_cast<const float4*>(base + (size_t)dd * VV);
            ax = fmaf(ev, a.x, ax); ay = fmaf(ev, a.y, ay);
            az = fmaf(ev, a.z, az); aw = fmaf(ev, a.w, aw);
        }
        part[w][l][0] = ax; part[w][l][1] = ay; part[w][l][2] = az; part[w][l][3] = aw;
        __syncthreads();
        int l2 = tid >> 2, j = tid & 3;
        float s = part[0][l2][j] + part[1][l2][j] + part[2][l2][j] + part[3][l2][j];
        out[(size_t)bk_ * VV + tid] = s;
        __syncthreads();
    }
}

extern "C" void kernel_launch(void* const* d_in, const int* in_sizes, int n_in,
                              void* d_out, int out_size, void* d_ws, size_t ws_size,
                              hipStream_t stream) {
    const float* qk    = (const float*)d_in[0];
    const float* Wk    = (const float*)d_in[1];
    const float* bk    = (const float*)d_in[2];
    const float* A     = (const float*)d_in[3];
    const float* usage = (const float*)d_in[4];
    const int*   midx  = (const int*)d_in[5];

    float* out   = (float*)d_out;
    float* retr  = out;                                 // B*TOPK*V = 524288
    float* conf  = out + (size_t)BB * TOPK * VV;        // 2048
    float* tsims = conf + BB * TOPK;                    // 2048

    // workspace layout: identical to the r2/r4/r9 PASSED layout
    double* ws64  = (double*)d_ws;
    double* e64   = ws64;                               // 65536 doubles
    double* qn64  = e64 + BB * KK;                      // 65536
    double* kn64  = qn64 + BB * KK;                     // 1,024,000
    double* sims  = kn64 + (size_t)MM * KK;             // 1,024,000
    int*    acts  = (int*)(sims + (size_t)BB * MM);     // 2048 ints

    k_proj<<<BB, 256, 0, stream>>>(qk, Wk, bk, e64, qn64);
    k_kn<<<MM, 256, 0, stream>>>(A, midx, kn64);
    dim3 g3((MM + BNS - 1) / BNS, BB / BMS);            // 63 x 16 = 1008 blocks
    k_sims<<<g3, 64, 0, stream>>>(qn64, kn64, sims);
    k_topk<<<BB, 256, 0, stream>>>(sims, midx, usage, conf, tsims, acts);
    k_retr<<<BB * TOPK, 256, 0, stream>>>(A, e64, acts, retr);
}

// Round 12
// 171.597 us; speedup vs baseline: 33.5840x; 33.5840x over previous
//
#include <hip/hip_runtime.h>
#include <math.h>

#define BB 256
#define KK 256
#define VV 256
#define MM 4000
#define TOPK 8

// K1: e64 = tanh(qk @ Wk^T + bk); qn64 = e64 / max(||e64||, 1e-8)
// (verbatim from round-2/4 PASSED kernel)
__global__ void k_proj(const float* __restrict__ qk, const float* __restrict__ Wk,
                       const float* __restrict__ bk, double* __restrict__ e64,
                       double* __restrict__ qn64) {
    int b = blockIdx.x, j = threadIdx.x;
    __shared__ float q[KK];
    __shared__ double red[256];
    q[j] = qk[b * KK + j];
    __syncthreads();
    const float* w = Wk + (size_t)j * KK;
    double acc = 0.0;
#pragma unroll 4
    for (int d = 0; d < KK; ++d) acc += (double)q[d] * (double)w[d];
    double val = tanh(acc + (double)bk[j]);
    e64[b * KK + j] = val;
    red[j] = val * val;
    __syncthreads();
    for (int s = 128; s > 0; s >>= 1) {
        if (j < s) red[j] += red[j + s];
        __syncthreads();
    }
    double nrm = fmax(sqrt(red[0]), 1e-8);
    qn64[b * KK + j] = val / nrm;
}

// K2: gather stored_keys = A[midx[m], k, 0]; kn64 = row / max(||row||, 1e-8)
// (verbatim from round-2/4 PASSED kernel)
__global__ void k_kn(const float* __restrict__ A, const int* __restrict__ midx,
                     double* __restrict__ kn64) {
    int m = blockIdx.x, t = threadIdx.x;
    size_t n = (size_t)midx[m];
    double val = (double)A[n * (size_t)(KK * VV) + (size_t)t * VV];
    __shared__ double red[256];
    red[t] = val * val;
    __syncthreads();
    for (int s = 128; s > 0; s >>= 1) {
        if (t < s) red[t] += red[t + s];
        __syncthreads();
    }
    double nrm = fmax(sqrt(red[0]), 1e-8);
    kn64[(size_t)m * KK + t] = val / nrm;
}

// K3 v4: sims64 = qn64 @ kn64^T, f64. Conflict-free LDS by construction:
//  - layout [row][k] with ODD stride 17 (no transpose in LDS);
//  - staging writes run along k per lane: banks (4(tid&7)+2(tid>>3))%32, ~2-way (free);
//  - compute kv reads use STRIDED m-columns (tx+16c): banks (2tx+2i)%32,
//    16 distinct -> conflict-free; q reads broadcast within tx-groups.
// Tile 8x64, 1 wave/block, grid 63x32 = 2016 blocks => 2 waves/SIMD.
// Double-buffered, loads-early/writes-late (v3b schedule).
// Per-accumulator k-order sequential 0..255 => sims bit-identical to r9.
// r11 PMC basis: old k_sims had 8.36e8 LDS bank conflicts/dispatch (8-way
// on ksT column writes: stride 72 => 16*kc = 0 mod 32 for even kc).
#define BMS 8
#define BNS 64
#define KS  16
#define LSTR 17
__global__ void __launch_bounds__(64) k_sims(
        const double* __restrict__ qn, const double* __restrict__ kn,
        double* __restrict__ sims) {
    __shared__ double qs[2][BMS][LSTR];
    __shared__ double ks[2][BNS][LSTR];
    int tid = threadIdx.x;
    int tx = tid & 15, ty = tid >> 4;        // tx: m (strided x4), ty: b (x2 rows)
    int m0 = blockIdx.x * BNS, b0 = blockIdx.y * BMS;
    // staging maps (global loads 16B-aligned, 128B-contiguous per 8 lanes)
    int qr  = tid >> 3;          // 0..7  b-row
    int qc2 = (tid & 7) * 2;     // k-col (double2)
    int krr = tid >> 3;          // m-row base (0..7), +8*s
    int kc  = (tid & 7) * 2;     // k-col (double2)
    const double* qrow = qn + (size_t)(b0 + qr) * KK;
    double acc[2][4] = {};

    // prologue: stage k-tile 0 into buf 0
    {
        double2 qreg; double2 kreg[8]; int rr[8];
        qreg = *(const double2*)(qrow + qc2);
#pragma unroll
        for (int s = 0; s < 8; ++s) {
            int r = krr + s * 8; rr[s] = r;
            int mrow = m0 + r;
            const double* kp = kn + (size_t)(mrow < MM ? mrow : 0) * KK + kc;
            kreg[s] = (mrow < MM) ? *(const double2*)kp : make_double2(0.0, 0.0);
        }
        qs[0][qr][qc2]     = qreg.x;
        qs[0][qr][qc2 + 1] = qreg.y;
#pragma unroll
        for (int s = 0; s < 8; ++s) {
            ks[0][rr[s]][kc]     = kreg[s].x;
            ks[0][rr[s]][kc + 1] = kreg[s].y;
        }
    }
    __syncthreads();

    for (int t = 0; t < KK / KS; ++t) {
        int cur = t & 1;
        double2 qreg; double2 kreg[8]; int rr[8];
        bool have = (t < KK / KS - 1);
        if (have) {                       // issue next tile's loads EARLY
            int kk2 = (t + 1) * KS;
            qreg = *(const double2*)(qrow + kk2 + qc2);
#pragma unroll
            for (int s = 0; s < 8; ++s) {
                int r = krr + s * 8; rr[s] = r;
                int mrow = m0 + r;
                const double* kp = kn + (size_t)(mrow < MM ? mrow : 0) * KK + kk2 + kc;
                kreg[s] = (mrow < MM) ? *(const double2*)kp : make_double2(0.0, 0.0);
            }
        }
        // compute on buf cur (hides in-flight global loads)
#pragma unroll
        for (int i = 0; i < KS; ++i) {
            double qv[2], kv[4];
#pragma unroll
            for (int a = 0; a < 2; ++a) qv[a] = qs[cur][ty * 2 + a][i];
#pragma unroll
            for (int c = 0; c < 4; ++c) kv[c] = ks[cur][tx + 16 * c][i];
#pragma unroll
            for (int a = 0; a < 2; ++a)
#pragma unroll
                for (int c = 0; c < 4; ++c)
                    acc[a][c] += qv[a] * kv[c];
        }
        if (have) {                       // LDS writes LATE
            int nxt = cur ^ 1;
            qs[nxt][qr][qc2]     = qreg.x;
            qs[nxt][qr][qc2 + 1] = qreg.y;
#pragma unroll
            for (int s = 0; s < 8; ++s) {
                ks[nxt][rr[s]][kc]     = kreg[s].x;
                ks[nxt][rr[s]][kc + 1] = kreg[s].y;
            }
        }
        __syncthreads();
    }
#pragma unroll
    for (int a = 0; a < 2; ++a) {
        int bb = b0 + ty * 2 + a;
#pragma unroll
        for (int c = 0; c < 4; ++c) {
            int mm2 = m0 + tx + 16 * c;
            if (mm2 < MM) sims[(size_t)bb * MM + mm2] = acc[a][c];
        }
    }
}

// K4: per-row top-8 (value desc, stable by index) in f64 + confidences
// (verbatim from round-2 PASSED kernel)
__global__ void k_topk(const double* __restrict__ sims, const int* __restrict__ midx,
                       const float* __restrict__ usage, float* __restrict__ out_conf,
                       float* __restrict__ out_sims, int* __restrict__ acts) {
    int b = blockIdx.x, t = threadIdx.x;
    double v[TOPK];
    int id[TOPK];
#pragma unroll
    for (int i = 0; i < TOPK; ++i) { v[i] = -INFINITY; id[i] = 0x7fffffff; }
    const double* row = sims + (size_t)b * MM;
    for (int m = t; m < MM; m += 256) {
        double x = row[m];
        if (x > v[TOPK - 1]) {
            v[TOPK - 1] = x; id[TOPK - 1] = m;
#pragma unroll
            for (int i = TOPK - 1; i > 0; --i) {
                if (v[i] > v[i - 1]) {  // strict: equal values keep smaller index first
                    double tv = v[i]; v[i] = v[i - 1]; v[i - 1] = tv;
                    int ti = id[i]; id[i] = id[i - 1]; id[i - 1] = ti;
                }
            }
        }
    }
    __shared__ double sv[256 * TOPK];
    __shared__ int si[256 * TOPK];
#pragma unroll
    for (int i = 0; i < TOPK; ++i) { sv[t * TOPK + i] = v[i]; si[t * TOPK + i] = id[i]; }
    __syncthreads();
    for (int stride = 128; stride > 0; stride >>= 1) {
        if (t < stride) {
            double* av = &sv[t * TOPK];
            int*    ai = &si[t * TOPK];
            double* bv = &sv[(t + stride) * TOPK];
            int*    bi = &si[(t + stride) * TOPK];
            double mv[TOPK]; int mi[TOPK];
            int pa = 0, pb = 0;
#pragma unroll
            for (int i = 0; i < TOPK; ++i) {
                double va = av[pa], vb = bv[pb];
                bool takeA = (va > vb) || (va == vb && ai[pa] < bi[pb]);
                if (takeA) { mv[i] = va; mi[i] = ai[pa]; ++pa; }
                else       { mv[i] = vb; mi[i] = bi[pb]; ++pb; }
            }
#pragma unroll
            for (int i = 0; i < TOPK; ++i) { av[i] = mv[i]; ai[i] = mi[i]; }
        }
        __syncthreads();
    }
    if (t < TOPK) {
        double val = sv[t];
        int idx = si[t];
        int actual = midx[idx];
        out_sims[b * TOPK + t] = (float)val;
        out_conf[b * TOPK + t] = (float)(val * (1.0 + log1p((double)usage[actual])));
        acts[b * TOPK + t] = actual;
    }
}

// K5: retrieved[b,k,v] = sum_d e[b,d] * A[acts[b,k], d, v]
// float4 loads, 4 waves split the d-range, LDS reduce.
// (verbatim from round-4/9 PASSED kernel; r10 dedup reverted — neutral)
__global__ void __launch_bounds__(256) k_retr(
        const float* __restrict__ A, const double* __restrict__ e64,
        const int* __restrict__ acts, float* __restrict__ out) {
    int bk_ = blockIdx.x;        // b*TOPK + k
    int b = bk_ >> 3;
    int tid = threadIdx.x;
    int w = tid >> 6, l = tid & 63;
    size_t n = (size_t)acts[bk_];
    const float* Ap = A + n * (size_t)(KK * VV);
    __shared__ float es[KK];
    __shared__ float part[4][64][4];
    es[tid] = (float)e64[b * KK + tid];
    __syncthreads();
    float ax = 0.f, ay = 0.f, az = 0.f, aw = 0.f;
    const float* base = Ap + (size_t)(w * 64) * VV + 4 * l;
#pragma unroll 8
    for (int dd = 0; dd < 64; ++dd) {
        float ev = es[w * 64 + dd];
        const float4 a = *reinterpret_cast<const float4*>(base + (size_t)dd * VV);
        ax = fmaf(ev, a.x, ax); ay = fmaf(ev, a.y, ay);
        az = fmaf(ev, a.z, az); aw = fmaf(ev, a.w, aw);
    }
    part[w][l][0] = ax; part[w][l][1] = ay; part[w][l][2] = az; part[w][l][3] = aw;
    __syncthreads();
    int l2 = tid >> 2, j = tid & 3;
    float s = part[0][l2][j] + part[1][l2][j] + part[2][l2][j] + part[3][l2][j];
    out[(size_t)bk_ * VV + tid] = s;   // 4*l2 + j == tid
}

extern "C" void kernel_launch(void* const* d_in, const int* in_sizes, int n_in,
                              void* d_out, int out_size, void* d_ws, size_t ws_size,
                              hipStream_t stream) {
    const float* qk    = (const float*)d_in[0];
    const float* Wk    = (const float*)d_in[1];
    const float* bk    = (const float*)d_in[2];
    const float* A     = (const float*)d_in[3];
    const float* usage = (const float*)d_in[4];
    const int*   midx  = (const int*)d_in[5];

    float* out   = (float*)d_out;
    float* retr  = out;                                 // B*TOPK*V = 524288
    float* conf  = out + (size_t)BB * TOPK * VV;        // 2048
    float* tsims = conf + BB * TOPK;                    // 2048

    // workspace layout: identical to the r2/r4/r9 PASSED layout
    double* ws64  = (double*)d_ws;
    double* e64   = ws64;                               // 65536 doubles
    double* qn64  = e64 + BB * KK;                      // 65536
    double* kn64  = qn64 + BB * KK;                     // 1,024,000
    double* sims  = kn64 + (size_t)MM * KK;             // 1,024,000
    int*    acts  = (int*)(sims + (size_t)BB * MM);     // 2048 ints

    k_proj<<<BB, 256, 0, stream>>>(qk, Wk, bk, e64, qn64);
    k_kn<<<MM, 256, 0, stream>>>(A, midx, kn64);
    dim3 g3((MM + BNS - 1) / BNS, BB / BMS);            // 63 x 32 = 2016 blocks
    k_sims<<<g3, 64, 0, stream>>>(qn64, kn64, sims);
    k_topk<<<BB, 256, 0, stream>>>(sims, midx, usage, conf, tsims, acts);
    k_retr<<<BB * TOPK, 256, 0, stream>>>(A, e64, acts, retr);
}

// Round 14
// 167.153 us; speedup vs baseline: 34.4770x; 1.0266x over previous
//
#include <hip/hip_runtime.h>
#include <math.h>

#define BB 256
#define KK 256
#define VV 256
#define MM 4000
#define TOPK 8

// K1: e64 = tanh(qk @ Wk^T + bk); qn64 = e64 / max(||e64||, 1e-8)
// (verbatim from round-2/4 PASSED kernel — FROZEN)
__global__ void k_proj(const float* __restrict__ qk, const float* __restrict__ Wk,
                       const float* __restrict__ bk, double* __restrict__ e64,
                       double* __restrict__ qn64) {
    int b = blockIdx.x, j = threadIdx.x;
    __shared__ float q[KK];
    __shared__ double red[256];
    q[j] = qk[b * KK + j];
    __syncthreads();
    const float* w = Wk + (size_t)j * KK;
    double acc = 0.0;
#pragma unroll 4
    for (int d = 0; d < KK; ++d) acc += (double)q[d] * (double)w[d];
    double val = tanh(acc + (double)bk[j]);
    e64[b * KK + j] = val;
    red[j] = val * val;
    __syncthreads();
    for (int s = 128; s > 0; s >>= 1) {
        if (j < s) red[j] += red[j + s];
        __syncthreads();
    }
    double nrm = fmax(sqrt(red[0]), 1e-8);
    qn64[b * KK + j] = val / nrm;
}

// K2: gather stored_keys = A[midx[m], k, 0]; kn64 = row / max(||row||, 1e-8)
// (verbatim from round-2/4 PASSED kernel — FROZEN)
__global__ void k_kn(const float* __restrict__ A, const int* __restrict__ midx,
                     double* __restrict__ kn64) {
    int m = blockIdx.x, t = threadIdx.x;
    size_t n = (size_t)midx[m];
    double val = (double)A[n * (size_t)(KK * VV) + (size_t)t * VV];
    __shared__ double red[256];
    red[t] = val * val;
    __syncthreads();
    for (int s = 128; s > 0; s >>= 1) {
        if (t < s) red[t] += red[t + s];
        __syncthreads();
    }
    double nrm = fmax(sqrt(red[0]), 1e-8);
    kn64[(size_t)m * KK + t] = val / nrm;
}

// K3 v5: sims64 = qn64 @ kn64^T, f64, writes full sims to global (selection
// chain untouched). Same conflict-free [row][k] stride-17 layout and
// double-buffer schedule as r12's v4; tile scaled BMS 8->32 (256 threads,
// 8 outputs/thread) to cut kn64 L3 re-reads 4x (256MB -> 64MB).
// Per-accumulator k-order sequential 0..255 => sims bit-identical to r12.
#define BMS 32
#define BNS 64
#define KS  16
#define LSTR 17
__global__ void __launch_bounds__(256) k_sims(
        const double* __restrict__ qn, const double* __restrict__ kn,
        double* __restrict__ sims) {
    __shared__ double qs[2][BMS][LSTR];   // 2*32*17*8 = 8704 B
    __shared__ double ks[2][BNS][LSTR];   // 2*64*17*8 = 17408 B
    int tid = threadIdx.x;                // 0..255
    int tx = tid & 15, ty = tid >> 4;     // tx: m-group (strided x4), ty: 0..15 (2 b-rows each)
    int m0 = blockIdx.x * BNS, b0 = blockIdx.y * BMS;
    // staging maps
    int qr = tid >> 3;                    // 0..31  b-row, one double2 per thread
    int qc2 = (tid & 7) * 2;              // k-col (double2)
    int krb = tid >> 3;                   // m-row base (0..31), +32*s
    int kc  = (tid & 7) * 2;              // k-col (double2)
    const double* qrow = qn + (size_t)(b0 + qr) * KK;
    double acc[2][4] = {};

    {   // prologue: stage k-tile 0 into buf 0
        double2 qreg; double2 kreg[2]; int rr[2];
        qreg = *(const double2*)(qrow + qc2);
#pragma unroll
        for (int s = 0; s < 2; ++s) {
            int r = krb + s * 32; rr[s] = r;
            int mrow = m0 + r;
            const double* kp = kn + (size_t)(mrow < MM ? mrow : 0) * KK + kc;
            kreg[s] = (mrow < MM) ? *(const double2*)kp : make_double2(0.0, 0.0);
        }
        qs[0][qr][qc2]     = qreg.x;
        qs[0][qr][qc2 + 1] = qreg.y;
#pragma unroll
        for (int s = 0; s < 2; ++s) {
            ks[0][rr[s]][kc]     = kreg[s].x;
            ks[0][rr[s]][kc + 1] = kreg[s].y;
        }
    }
    __syncthreads();

    for (int t = 0; t < KK / KS; ++t) {
        int cur = t & 1;
        double2 qreg; double2 kreg[2]; int rr[2];
        bool have = (t < KK / KS - 1);
        if (have) {                       // issue next tile's loads EARLY
            int kk2 = (t + 1) * KS;
            qreg = *(const double2*)(qrow + kk2 + qc2);
#pragma unroll
            for (int s = 0; s < 2; ++s) {
                int r = krb + s * 32; rr[s] = r;
                int mrow = m0 + r;
                const double* kp = kn + (size_t)(mrow < MM ? mrow : 0) * KK + kk2 + kc;
                kreg[s] = (mrow < MM) ? *(const double2*)kp : make_double2(0.0, 0.0);
            }
        }
        // compute on buf cur (hides in-flight global loads)
#pragma unroll
        for (int i = 0; i < KS; ++i) {
            double qv[2], kv[4];
#pragma unroll
            for (int a = 0; a < 2; ++a) qv[a] = qs[cur][ty * 2 + a][i];
#pragma unroll
            for (int c = 0; c < 4; ++c) kv[c] = ks[cur][tx + 16 * c][i];
#pragma unroll
            for (int a = 0; a < 2; ++a)
#pragma unroll
                for (int c = 0; c < 4; ++c)
                    acc[a][c] += qv[a] * kv[c];
        }
        if (have) {                       // LDS writes LATE
            int nxt = cur ^ 1;
            qs[nxt][qr][qc2]     = qreg.x;
            qs[nxt][qr][qc2 + 1] = qreg.y;
#pragma unroll
            for (int s = 0; s < 2; ++s) {
                ks[nxt][rr[s]][kc]     = kreg[s].x;
                ks[nxt][rr[s]][kc + 1] = kreg[s].y;
            }
        }
        __syncthreads();
    }
#pragma unroll
    for (int a = 0; a < 2; ++a) {
        int bb = b0 + ty * 2 + a;
#pragma unroll
        for (int c = 0; c < 4; ++c) {
            int mm2 = m0 + tx + 16 * c;
            if (mm2 < MM) sims[(size_t)bb * MM + mm2] = acc[a][c];
        }
    }
}

// K4: per-row top-8 (value desc, stable by index) in f64 + confidences
// (verbatim from round-2 PASSED kernel — FROZEN)
__global__ void k_topk(const double* __restrict__ sims, const int* __restrict__ midx,
                       const float* __restrict__ usage, float* __restrict__ out_conf,
                       float* __restrict__ out_sims, int* __restrict__ acts) {
    int b = blockIdx.x, t = threadIdx.x;
    double v[TOPK];
    int id[TOPK];
#pragma unroll
    for (int i = 0; i < TOPK; ++i) { v[i] = -INFINITY; id[i] = 0x7fffffff; }
    const double* row = sims + (size_t)b * MM;
    for (int m = t; m < MM; m += 256) {
        double x = row[m];
        if (x > v[TOPK - 1]) {
            v[TOPK - 1] = x; id[TOPK - 1] = m;
#pragma unroll
            for (int i = TOPK - 1; i > 0; --i) {
                if (v[i] > v[i - 1]) {  // strict: equal values keep smaller index first
                    double tv = v[i]; v[i] = v[i - 1]; v[i - 1] = tv;
                    int ti = id[i]; id[i] = id[i - 1]; id[i - 1] = ti;
                }
            }
        }
    }
    __shared__ double sv[256 * TOPK];
    __shared__ int si[256 * TOPK];
#pragma unroll
    for (int i = 0; i < TOPK; ++i) { sv[t * TOPK + i] = v[i]; si[t * TOPK + i] = id[i]; }
    __syncthreads();
    for (int stride = 128; stride > 0; stride >>= 1) {
        if (t < stride) {
            double* av = &sv[t * TOPK];
            int*    ai = &si[t * TOPK];
            double* bv = &sv[(t + stride) * TOPK];
            int*    bi = &si[(t + stride) * TOPK];
            double mv[TOPK]; int mi[TOPK];
            int pa = 0, pb = 0;
#pragma unroll
            for (int i = 0; i < TOPK; ++i) {
                double va = av[pa], vb = bv[pb];
                bool takeA = (va > vb) || (va == vb && ai[pa] < bi[pb]);
                if (takeA) { mv[i] = va; mi[i] = ai[pa]; ++pa; }
                else       { mv[i] = vb; mi[i] = bi[pb]; ++pb; }
            }
#pragma unroll
            for (int i = 0; i < TOPK; ++i) { av[i] = mv[i]; ai[i] = mi[i]; }
        }
        __syncthreads();
    }
    if (t < TOPK) {
        double val = sv[t];
        int idx = si[t];
        int actual = midx[idx];
        out_sims[b * TOPK + t] = (float)val;
        out_conf[b * TOPK + t] = (float)(val * (1.0 + log1p((double)usage[actual])));
        acts[b * TOPK + t] = actual;
    }
}

// K5: retrieved[b,k,v] = sum_d e[b,d] * A[acts[b,k], d, v]
// (verbatim from round-4/9/12 PASSED kernel — FROZEN)
__global__ void __launch_bounds__(256) k_retr(
        const float* __restrict__ A, const double* __restrict__ e64,
        const int* __restrict__ acts, float* __restrict__ out) {
    int bk_ = blockIdx.x;        // b*TOPK + k
    int b = bk_ >> 3;
    int tid = threadIdx.x;
    int w = tid >> 6, l = tid & 63;
    size_t n = (size_t)acts[bk_];
    const float* Ap = A + n * (size_t)(KK * VV);
    __shared__ float es[KK];
    __shared__ float part[4][64][4];
    es[tid] = (float)e64[b * KK + tid];
    __syncthreads();
    float ax = 0.f, ay = 0.f, az = 0.f, aw = 0.f;
    const float* base = Ap + (size_t)(w * 64) * VV + 4 * l;
#pragma unroll 8
    for (int dd = 0; dd < 64; ++dd) {
        float ev = es[w * 64 + dd];
        const float4 a = *reinterpret_cast<const float4*>(base + (size_t)dd * VV);
        ax = fmaf(ev, a.x, ax); ay = fmaf(ev, a.y, ay);
        az = fmaf(ev, a.z, az); aw = fmaf(ev, a.w, aw);
    }
    part[w][l][0] = ax; part[w][l][1] = ay; part[w][l][2] = az; part[w][l][3] = aw;
    __syncthreads();
    int l2 = tid >> 2, j = tid & 3;
    float s = part[0][l2][j] + part[1][l2][j] + part[2][l2][j] + part[3][l2][j];
    out[(size_t)bk_ * VV + tid] = s;   // 4*l2 + j == tid
}

extern "C" void kernel_launch(void* const* d_in, const int* in_sizes, int n_in,
                              void* d_out, int out_size, void* d_ws, size_t ws_size,
                              hipStream_t stream) {
    const float* qk    = (const float*)d_in[0];
    const float* Wk    = (const float*)d_in[1];
    const float* bk    = (const float*)d_in[2];
    const float* A     = (const float*)d_in[3];
    const float* usage = (const float*)d_in[4];
    const int*   midx  = (const int*)d_in[5];

    float* out   = (float*)d_out;
    float* retr  = out;                                 // B*TOPK*V = 524288
    float* conf  = out + (size_t)BB * TOPK * VV;        // 2048
    float* tsims = conf + BB * TOPK;                    // 2048

    // workspace layout: identical to the r2/r4/r9/r12 PASSED layout
    double* ws64  = (double*)d_ws;
    double* e64   = ws64;                               // 65536 doubles
    double* qn64  = e64 + BB * KK;                      // 65536
    double* kn64  = qn64 + BB * KK;                     // 1,024,000
    double* sims  = kn64 + (size_t)MM * KK;             // 1,024,000
    int*    acts  = (int*)(sims + (size_t)BB * MM);     // 2048 ints

    k_proj<<<BB, 256, 0, stream>>>(qk, Wk, bk, e64, qn64);
    k_kn<<<MM, 256, 0, stream>>>(A, midx, kn64);
    dim3 g3((MM + BNS - 1) / BNS, BB / BMS);            // 63 x 8 = 504 blocks
    k_sims<<<g3, 256, 0, stream>>>(qn64, kn64, sims);
    k_topk<<<BB, 256, 0, stream>>>(sims, midx, usage, conf, tsims, acts);
    k_retr<<<BB * TOPK, 256, 0, stream>>>(A, e64, acts, retr);
}

// Round 15
// 164.101 us; speedup vs baseline: 35.1181x; 1.0186x over previous
//
#include <hip/hip_runtime.h>
#include <math.h>

#define BB 256
#define KK 256
#define VV 256
#define MM 4000
#define TOPK 8

// K1: e64 = tanh(qk @ Wk^T + bk); qn64 = e64 / max(||e64||, 1e-8)
// (verbatim from round-2/4 PASSED kernel — FROZEN)
__global__ void k_proj(const float* __restrict__ qk, const float* __restrict__ Wk,
                       const float* __restrict__ bk, double* __restrict__ e64,
                       double* __restrict__ qn64) {
    int b = blockIdx.x, j = threadIdx.x;
    __shared__ float q[KK];
    __shared__ double red[256];
    q[j] = qk[b * KK + j];
    __syncthreads();
    const float* w = Wk + (size_t)j * KK;
    double acc = 0.0;
#pragma unroll 4
    for (int d = 0; d < KK; ++d) acc += (double)q[d] * (double)w[d];
    double val = tanh(acc + (double)bk[j]);
    e64[b * KK + j] = val;
    red[j] = val * val;
    __syncthreads();
    for (int s = 128; s > 0; s >>= 1) {
        if (j < s) red[j] += red[j + s];
        __syncthreads();
    }
    double nrm = fmax(sqrt(red[0]), 1e-8);
    qn64[b * KK + j] = val / nrm;
}

// K2: gather stored_keys = A[midx[m], k, 0]; kn64 = row / max(||row||, 1e-8)
// (verbatim from round-2/4 PASSED kernel — FROZEN)
__global__ void k_kn(const float* __restrict__ A, const int* __restrict__ midx,
                     double* __restrict__ kn64) {
    int m = blockIdx.x, t = threadIdx.x;
    size_t n = (size_t)midx[m];
    double val = (double)A[n * (size_t)(KK * VV) + (size_t)t * VV];
    __shared__ double red[256];
    red[t] = val * val;
    __syncthreads();
    for (int s = 128; s > 0; s >>= 1) {
        if (t < s) red[t] += red[t + s];
        __syncthreads();
    }
    double nrm = fmax(sqrt(red[0]), 1e-8);
    kn64[(size_t)m * KK + t] = val / nrm;
}

// K3 v6: sims64 = qn64 @ kn64^T, f64. Single change vs r14's v5: 4x4 register
// blocking (0.5 LDS b64-reads/FMA vs 0.75) on the SAME clean [row][k]
// stride-17 layout. BMS=32, BNS=128, 256 thr, grid 32x8 = 256 blocks (1/CU).
// r7's 4x4 "neutral" is explained by its (then-unknown) 8-way staging write
// conflict (r11 PMC); this layout's staging/read banks are 2-way max.
// Per-accumulator k-order sequential 0..255, same expression form =>
// sims bit-identical to r12/r14 (absmax invariant 0.001953125).
#define BMS 32
#define BNS 128
#define KS  16
#define LSTR 17
__global__ void __launch_bounds__(256) k_sims(
        const double* __restrict__ qn, const double* __restrict__ kn,
        double* __restrict__ sims) {
    __shared__ double qs[2][BMS][LSTR];   // 8704 B
    __shared__ double ks[2][BNS][LSTR];   // 34816 B
    int tid = threadIdx.x;                // 0..255
    int tx = tid & 31, ty = tid >> 5;     // tx: m-group (4 cols, stride 32); ty: 0..7 (4 b-rows)
    int m0 = blockIdx.x * BNS, b0 = blockIdx.y * BMS;
    // staging maps
    int qr  = tid >> 3;                   // 0..31  b-row, one double2/thread
    int qc2 = (tid & 7) * 2;              // k-col (double2)
    int krb = tid >> 3;                   // m-row base (0..31), +32*s (s=0..3)
    int kc  = (tid & 7) * 2;              // k-col (double2)
    const double* qrow = qn + (size_t)(b0 + qr) * KK;
    double acc[4][4] = {};

    {   // prologue: stage k-tile 0 into buf 0
        double2 qreg; double2 kreg[4]; int rr[4];
        qreg = *(const double2*)(qrow + qc2);
#pragma unroll
        for (int s = 0; s < 4; ++s) {
            int r = krb + s * 32; rr[s] = r;
            int mrow = m0 + r;
            const double* kp = kn + (size_t)(mrow < MM ? mrow : 0) * KK + kc;
            kreg[s] = (mrow < MM) ? *(const double2*)kp : make_double2(0.0, 0.0);
        }
        qs[0][qr][qc2]     = qreg.x;
        qs[0][qr][qc2 + 1] = qreg.y;
#pragma unroll
        for (int s = 0; s < 4; ++s) {
            ks[0][rr[s]][kc]     = kreg[s].x;
            ks[0][rr[s]][kc + 1] = kreg[s].y;
        }
    }
    __syncthreads();

    for (int t = 0; t < KK / KS; ++t) {
        int cur = t & 1;
        double2 qreg; double2 kreg[4]; int rr[4];
        bool have = (t < KK / KS - 1);
        if (have) {                       // issue next tile's loads EARLY
            int kk2 = (t + 1) * KS;
            qreg = *(const double2*)(qrow + kk2 + qc2);
#pragma unroll
            for (int s = 0; s < 4; ++s) {
                int r = krb + s * 32; rr[s] = r;
                int mrow = m0 + r;
                const double* kp = kn + (size_t)(mrow < MM ? mrow : 0) * KK + kk2 + kc;
                kreg[s] = (mrow < MM) ? *(const double2*)kp : make_double2(0.0, 0.0);
            }
        }
        // compute on buf cur (hides in-flight global loads)
#pragma unroll
        for (int i = 0; i < KS; ++i) {
            double qv[4], kv[4];
#pragma unroll
            for (int a = 0; a < 4; ++a) qv[a] = qs[cur][ty * 4 + a][i];
#pragma unroll
            for (int c = 0; c < 4; ++c) kv[c] = ks[cur][tx + 32 * c][i];
#pragma unroll
            for (int a = 0; a < 4; ++a)
#pragma unroll
                for (int c = 0; c < 4; ++c)
                    acc[a][c] += qv[a] * kv[c];
        }
        if (have) {                       // LDS writes LATE
            int nxt = cur ^ 1;
            qs[nxt][qr][qc2]     = qreg.x;
            qs[nxt][qr][qc2 + 1] = qreg.y;
#pragma unroll
            for (int s = 0; s < 4; ++s) {
                ks[nxt][rr[s]][kc]     = kreg[s].x;
                ks[nxt][rr[s]][kc + 1] = kreg[s].y;
            }
        }
        __syncthreads();
    }
#pragma unroll
    for (int a = 0; a < 4; ++a) {
        int bb = b0 + ty * 4 + a;
#pragma unroll
        for (int c = 0; c < 4; ++c) {
            int mm2 = m0 + tx + 32 * c;
            if (mm2 < MM) sims[(size_t)bb * MM + mm2] = acc[a][c];
        }
    }
}

// K4: per-row top-8 (value desc, stable by index) in f64 + confidences
// (verbatim from round-2 PASSED kernel — FROZEN)
__global__ void k_topk(const double* __restrict__ sims, const int* __restrict__ midx,
                       const float* __restrict__ usage, float* __restrict__ out_conf,
                       float* __restrict__ out_sims, int* __restrict__ acts) {
    int b = blockIdx.x, t = threadIdx.x;
    double v[TOPK];
    int id[TOPK];
#pragma unroll
    for (int i = 0; i < TOPK; ++i) { v[i] = -INFINITY; id[i] = 0x7fffffff; }
    const double* row = sims + (size_t)b * MM;
    for (int m = t; m < MM; m += 256) {
        double x = row[m];
        if (x > v[TOPK - 1]) {
            v[TOPK - 1] = x; id[TOPK - 1] = m;
#pragma unroll
            for (int i = TOPK - 1; i > 0; --i) {
                if (v[i] > v[i - 1]) {  // strict: equal values keep smaller index first
                    double tv = v[i]; v[i] = v[i - 1]; v[i - 1] = tv;
                    int ti = id[i]; id[i] = id[i - 1]; id[i - 1] = ti;
                }
            }
        }
    }
    __shared__ double sv[256 * TOPK];
    __shared__ int si[256 * TOPK];
#pragma unroll
    for (int i = 0; i < TOPK; ++i) { sv[t * TOPK + i] = v[i]; si[t * TOPK + i] = id[i]; }
    __syncthreads();
    for (int stride = 128; stride > 0; stride >>= 1) {
        if (t < stride) {
            double* av = &sv[t * TOPK];
            int*    ai = &si[t * TOPK];
            double* bv = &sv[(t + stride) * TOPK];
            int*    bi = &si[(t + stride) * TOPK];
            double mv[TOPK]; int mi[TOPK];
            int pa = 0, pb = 0;
#pragma unroll
            for (int i = 0; i < TOPK; ++i) {
                double va = av[pa], vb = bv[pb];
                bool takeA = (va > vb) || (va == vb && ai[pa] < bi[pb]);
                if (takeA) { mv[i] = va; mi[i] = ai[pa]; ++pa; }
                else       { mv[i] = vb; mi[i] = bi[pb]; ++pb; }
            }
#pragma unroll
            for (int i = 0; i < TOPK; ++i) { av[i] = mv[i]; ai[i] = mi[i]; }
        }
        __syncthreads();
    }
    if (t < TOPK) {
        double val = sv[t];
        int idx = si[t];
        int actual = midx[idx];
        out_sims[b * TOPK + t] = (float)val;
        out_conf[b * TOPK + t] = (float)(val * (1.0 + log1p((double)usage[actual])));
        acts[b * TOPK + t] = actual;
    }
}

// K5: retrieved[b,k,v] = sum_d e[b,d] * A[acts[b,k], d, v]
// (verbatim from round-4/9/12/14 PASSED kernel — FROZEN)
__global__ void __launch_bounds__(256) k_retr(
        const float* __restrict__ A, const double* __restrict__ e64,
        const int* __restrict__ acts, float* __restrict__ out) {
    int bk_ = blockIdx.x;        // b*TOPK + k
    int b = bk_ >> 3;
    int tid = threadIdx.x;
    int w = tid >> 6, l = tid & 63;
    size_t n = (size_t)acts[bk_];
    const float* Ap = A + n * (size_t)(KK * VV);
    __shared__ float es[KK];
    __shared__ float part[4][64][4];
    es[tid] = (float)e64[b * KK + tid];
    __syncthreads();
    float ax = 0.f, ay = 0.f, az = 0.f, aw = 0.f;
    const float* base = Ap + (size_t)(w * 64) * VV + 4 * l;
#pragma unroll 8
    for (int dd = 0; dd < 64; ++dd) {
        float ev = es[w * 64 + dd];
        const float4 a = *reinterpret_cast<const float4*>(base + (size_t)dd * VV);
        ax = fmaf(ev, a.x, ax); ay = fmaf(ev, a.y, ay);
        az = fmaf(ev, a.z, az); aw = fmaf(ev, a.w, aw);
    }
    part[w][l][0] = ax; part[w][l][1] = ay; part[w][l][2] = az; part[w][l][3] = aw;
    __syncthreads();
    int l2 = tid >> 2, j = tid & 3;
    float s = part[0][l2][j] + part[1][l2][j] + part[2][l2][j] + part[3][l2][j];
    out[(size_t)bk_ * VV + tid] = s;   // 4*l2 + j == tid
}

extern "C" void kernel_launch(void* const* d_in, const int* in_sizes, int n_in,
                              void* d_out, int out_size, void* d_ws, size_t ws_size,
                              hipStream_t stream) {
    const float* qk    = (const float*)d_in[0];
    const float* Wk    = (const float*)d_in[1];
    const float* bk    = (const float*)d_in[2];
    const float* A     = (const float*)d_in[3];
    const float* usage = (const float*)d_in[4];
    const int*   midx  = (const int*)d_in[5];

    float* out   = (float*)d_out;
    float* retr  = out;                                 // B*TOPK*V = 524288
    float* conf  = out + (size_t)BB * TOPK * VV;        // 2048
    float* tsims = conf + BB * TOPK;                    // 2048

    // workspace layout: identical to the r2/r4/r9/r12/r14 PASSED layout
    double* ws64  = (double*)d_ws;
    double* e64   = ws64;                               // 65536 doubles
    double* qn64  = e64 + BB * KK;                      // 65536
    double* kn64  = qn64 + BB * KK;                     // 1,024,000
    double* sims  = kn64 + (size_t)MM * KK;             // 1,024,000
    int*    acts  = (int*)(sims + (size_t)BB * MM);     // 2048 ints

    // k_kn first: it is the long pole before k_sims; k_proj rides behind it.
    k_kn<<<MM, 256, 0, stream>>>(A, midx, kn64);
    k_proj<<<BB, 256, 0, stream>>>(qk, Wk, bk, e64, qn64);
    dim3 g3((MM + BNS - 1) / BNS, BB / BMS);            // 32 x 8 = 256 blocks
    k_sims<<<g3, 256, 0, stream>>>(qn64, kn64, sims);
    k_topk<<<BB, 256, 0, stream>>>(sims, midx, usage, conf, tsims, acts);
    k_retr<<<BB * TOPK, 256, 0, stream>>>(A, e64, acts, retr);
}